// Round 11
// baseline (97.472 us; speedup 1.0000x reference)
//
#include <hip/hip_runtime.h>

typedef unsigned int uint;
typedef unsigned short ushort;
typedef __attribute__((ext_vector_type(4))) uint   u32x4;
typedef __attribute__((ext_vector_type(8))) short  short8;
typedef __attribute__((ext_vector_type(8))) __bf16 bf16x8;
typedef __attribute__((ext_vector_type(4))) float  f32x4;

// Device pass: real gfx950 builtin. Host pass: inert asm fallback (never codegen'd).
__device__ __forceinline__ f32x4 mfma32(short8 a, short8 b, f32x4 c){
#if __has_builtin(__builtin_amdgcn_mfma_f32_16x16x32_bf16)
    return __builtin_amdgcn_mfma_f32_16x16x32_bf16(
        __builtin_bit_cast(bf16x8, a), __builtin_bit_cast(bf16x8, b), c, 0, 0, 0);
#else
    asm volatile("v_mfma_f32_16x16x32_bf16 %0, %1, %2, %0\n\ts_nop 7\n\ts_nop 7"
                 : "+v"(c) : "v"(a), "v"(b));
    return c;
#endif
}

__device__ __forceinline__ uint  fbits(float f){ return __builtin_bit_cast(uint, f); }
__device__ __forceinline__ float ibits(uint u){ return __builtin_bit_cast(float, u); }
__device__ __forceinline__ ushort rne_bf16(float f){
    uint u = fbits(f);
    return (ushort)((u + 0x7FFFu + ((u >> 16) & 1u)) >> 16);
}
// packed 2xf32 -> 2xbf16 (low = a, high = b); single HW op on gfx950
__device__ __forceinline__ uint cvtpk(float a, float b){
    uint r;
    asm("v_cvt_pk_bf16_f32 %0, %1, %2" : "=v"(r) : "v"(a), "v"(b));
    return r;
}

// ---------------- weight packing into per-lane K=32 MFMA fragments ----------------
// Slot convention (valid because A and B share the same (g,e)->k map, so the HW
// k-permutation cancels): slot (g=lane>>4, e=0..7) of the K=32 operand.
//  A1[t]: slot e -> channel c = 4g+(e&3); part = (e<4) ? hi : lo of W1[c][16t+m]
//  A2[p]: slot e -> hidden  = 16*(2p+(e>>2)) + 4g + (e&3); value = bf16(W2[hid][m])
//  b1f[t]: f32x4 = b1[16t+4g+r]  (C-in bias for layer 1)
// ws u32 layout: [0..1023] A1 (t*64+l)*4+reg ; [1024..1535] A2 (p*64+l)*4+reg ;
//                [1536..2559] b1f as f32 (t*64+l)*4+r
__global__ void pack_weights(const float* __restrict__ W1, const float* __restrict__ b1,
                             const float* __restrict__ W2, float* __restrict__ ws)
{
    const int e4 = threadIdx.x;         // 256 = 4 tiles * 64 lanes
    const int t = e4 >> 6, l = e4 & 63;
    const int g = l >> 4, m = l & 15;
    uint* wsu = (uint*)ws;

    // A1 tile t: hi part in K-half 0 (e=0..3), lo residual in K-half 1 (e=4..7)
    ushort el[8];
    #pragma unroll
    for (int i = 0; i < 8; ++i) {
        const int c = 4*g + (i & 3);
        const float w = W1[c * 64 + 16*t + m];   // W1 is (16,64) row-major
        const ushort hi = rne_bf16(w);
        if (i < 4) el[i] = hi;
        else       el[i] = rne_bf16(w - ibits(((uint)hi) << 16));  // lo residual
    }
    #pragma unroll
    for (int r = 0; r < 4; ++r)
        wsu[(t*64 + l)*4 + r] = (uint)el[2*r] | ((uint)el[2*r+1] << 16);

    // A2 pair p (only t<2): two 16-hidden tiles per K=32
    if (t < 2) {
        const int p = t;
        ushort e2[8];
        #pragma unroll
        for (int i = 0; i < 8; ++i) {
            const int hid = 16*(2*p + (i >> 2)) + 4*g + (i & 3);
            e2[i] = rne_bf16(W2[hid * 16 + m]);  // W2 is (64,16) row-major
        }
        #pragma unroll
        for (int r = 0; r < 4; ++r)
            wsu[1024 + (p*64 + l)*4 + r] = (uint)e2[2*r] | ((uint)e2[2*r+1] << 16);
    }

    // b1 fragment
    #pragma unroll
    for (int r = 0; r < 4; ++r)
        ws[1536 + (t*64 + l)*4 + r] = b1[16*t + 4*g + r];
}

// asm load with immediate byte offset off a fixed base pointer: the compiler
// cannot sink, split, or re-schedule these past each other (volatile order).
#define GLOAD(dst, base, OFF) \
    asm volatile("global_load_dwordx4 %0, %1, off offset:%c2" \
                 : "=v"(dst) : "v"(base), "i"(OFF) : "memory")
// counted wait + hard scheduling fence (rule #18: sched_barrier after waitcnt)
#define VWAIT(N) do { \
    asm volatile("s_waitcnt vmcnt(%c0)" :: "i"(N) : "memory"); \
    __builtin_amdgcn_sched_barrier(0); } while (0)

// ---------------- main kernel ----------------
// One wave = 16 rows; lane (n=l&15, g=l>>4) owns row n, channel window 4g..4g+3.
// ROUND 11: round 10's register pipeline was silently deleted by the compiler
// (VGPR=60 proves loads were sunk to their uses). Now the 3-stage rotating
// pipeline is enforced with inline-asm global_load_dwordx4 + counted
// s_waitcnt vmcnt(6) per body (AITER/HK pattern: never drain to 0 mid-loop).
// FIFO: prologue issues stages j=0,1,2 (9 loads); each body waits vmcnt(6)
// (retires exactly its stage's trio), consumes, reissues j+3. Tail waits 6,3,0.
// 6 MFMAs/neighbor (K=32); layer-1 C packs directly into layer-2 B fragment.
__global__ __launch_bounds__(256) __attribute__((amdgpu_waves_per_eu(4, 4)))
void subattn_mfma(const float* __restrict__ q, const float* __restrict__ k,
                  const float* __restrict__ v, const float* __restrict__ pe,
                  const float* __restrict__ ws, float* __restrict__ out)
{
    const int tid = threadIdx.x;
    const int wv  = tid >> 6;
    const int l   = tid & 63;
    const int n   = l & 15, g = l >> 4;
    const int grp = blockIdx.x * 4 + wv;
    const int rg  = grp * 16 + n;            // global row = bp*4 + h
    const int bp  = rg >> 2, h = rg & 3;

    // weight fragments: A1 16 + A2 8 + b1f 16 = 40 VGPRs persistent
    const u32x4* a1p = (const u32x4*)ws;
    const u32x4* a2p = (const u32x4*)(ws + 1024);
    const f32x4* bfp = (const f32x4*)(ws + 1536);
    short8 a1[4], a2[2];
    f32x4  b1f[4];
    #pragma unroll
    for (int t = 0; t < 4; ++t) {
        a1[t]  = __builtin_bit_cast(short8, a1p[t*64 + l]);
        b1f[t] = bfp[t*64 + l];
    }
    #pragma unroll
    for (int p = 0; p < 2; ++p) a2[p] = __builtin_bit_cast(short8, a2p[p*64 + l]);

    const size_t qoff  = (size_t)rg * 16 + g * 4;
    f32x4 qf = *(const f32x4*)(q + qoff);
    const size_t kbase = (size_t)bp * 576 + h * 16 + g * 4;   // 9*64 per bp
    const float* kq = k  + kbase;
    const float* pq = pe + kbase;
    const float* vq = v  + kbase;

    // pin weights + q into registers and drain all compiler-tracked loads so
    // the loop's manual vmcnt accounting is exact
    asm volatile("" : "+v"(qf), "+v"(a1[0]), "+v"(a1[1]), "+v"(a1[2]), "+v"(a1[3]));
    asm volatile("" : "+v"(a2[0]), "+v"(a2[1]),
                      "+v"(b1f[0]), "+v"(b1f[1]), "+v"(b1f[2]), "+v"(b1f[3]));
    asm volatile("s_waitcnt vmcnt(0)" ::: "memory");

    f32x4 lsum = {0.f, 0.f, 0.f, 0.f};
    f32x4 acc  = {0.f, 0.f, 0.f, 0.f};

    // 3 pipeline stages in named registers; issue order defines the vmcnt FIFO
    f32x4 k0, p0, v0, k1, p1, v1, k2, p2, v2;
    GLOAD(k0, kq, 0);    GLOAD(p0, pq, 0);    GLOAD(v0, vq, 0);
    GLOAD(k1, kq, 256);  GLOAD(p1, pq, 256);  GLOAD(v1, vq, 256);
    GLOAD(k2, kq, 512);  GLOAD(p2, pq, 512);  GLOAD(v2, vq, 512);

    // body: wait for stage trio (WN), consume, reissue stage for neighbor JN
#define BODY(KS, PS, VS, JN, WN)                                               \
    {                                                                          \
        VWAIT(WN);                                                             \
        const f32x4 x   = qf - KS + PS;                                        \
        const f32x4 vpl = VS + PS;                                             \
        if ((JN) < 9) {                                                        \
            GLOAD(KS, kq, (JN) * 256);                                         \
            GLOAD(PS, pq, (JN) * 256);                                         \
            GLOAD(VS, vq, (JN) * 256);                                         \
        }                                                                      \
        const uint xp0 = cvtpk(x.x, x.y);                                      \
        const uint xp1 = cvtpk(x.z, x.w);                                      \
        const u32x4 bxu = {xp0, xp1, xp0, xp1};                                \
        const short8 bx = __builtin_bit_cast(short8, bxu);                     \
        f32x4 c1_0 = mfma32(a1[0], bx, b1f[0]);                                \
        f32x4 c1_1 = mfma32(a1[1], bx, b1f[1]);                                \
        f32x4 c1_2 = mfma32(a1[2], bx, b1f[2]);                                \
        f32x4 c1_3 = mfma32(a1[3], bx, b1f[3]);                                \
        uint ph00, ph01, ph10, ph11, ph20, ph21, ph30, ph31;                   \
        ph00 = cvtpk(fmaxf(c1_0.x, 0.f), fmaxf(c1_0.y, 0.f));                  \
        ph01 = cvtpk(fmaxf(c1_0.z, 0.f), fmaxf(c1_0.w, 0.f));                  \
        ph10 = cvtpk(fmaxf(c1_1.x, 0.f), fmaxf(c1_1.y, 0.f));                  \
        ph11 = cvtpk(fmaxf(c1_1.z, 0.f), fmaxf(c1_1.w, 0.f));                  \
        ph20 = cvtpk(fmaxf(c1_2.x, 0.f), fmaxf(c1_2.y, 0.f));                  \
        ph21 = cvtpk(fmaxf(c1_2.z, 0.f), fmaxf(c1_2.w, 0.f));                  \
        ph30 = cvtpk(fmaxf(c1_3.x, 0.f), fmaxf(c1_3.y, 0.f));                  \
        ph31 = cvtpk(fmaxf(c1_3.z, 0.f), fmaxf(c1_3.w, 0.f));                  \
        const u32x4 bh0u = {ph00, ph01, ph10, ph11};                           \
        const u32x4 bh1u = {ph20, ph21, ph30, ph31};                           \
        f32x4 c2 = {0.f, 0.f, 0.f, 0.f};                                       \
        c2 = mfma32(a2[0], __builtin_bit_cast(short8, bh0u), c2);              \
        c2 = mfma32(a2[1], __builtin_bit_cast(short8, bh1u), c2);              \
        f32x4 ev;                                                              \
        ev.x = __expf(c2.x); ev.y = __expf(c2.y);                              \
        ev.z = __expf(c2.z); ev.w = __expf(c2.w);                              \
        lsum += ev;                                                            \
        acc  += ev * vpl;                                                      \
    }

    BODY(k0, p0, v0, 3, 6)
    BODY(k1, p1, v1, 4, 6)
    BODY(k2, p2, v2, 5, 6)
    BODY(k0, p0, v0, 6, 6)
    BODY(k1, p1, v1, 7, 6)
    BODY(k2, p2, v2, 8, 6)
    BODY(k0, p0, v0, 9, 6)
    BODY(k1, p1, v1, 9, 3)
    BODY(k2, p2, v2, 9, 0)
#undef BODY

    f32x4 o;
    o.x = __fdividef(acc.x, lsum.x); o.y = __fdividef(acc.y, lsum.y);
    o.z = __fdividef(acc.z, lsum.z); o.w = __fdividef(acc.w, lsum.w);
    *(f32x4*)(out + qoff) = o;
}

extern "C" void kernel_launch(void* const* d_in, const int* in_sizes, int n_in,
                              void* d_out, int out_size, void* d_ws, size_t ws_size,
                              hipStream_t stream) {
    const float* q  = (const float*)d_in[0];
    const float* k  = (const float*)d_in[1];
    const float* v  = (const float*)d_in[2];
    const float* pe = (const float*)d_in[3];
    const float* W1 = (const float*)d_in[4];
    const float* b1 = (const float*)d_in[5];
    const float* W2 = (const float*)d_in[6];
    // d_in[7] = b2: cancels in softmax over neighbors.
    float* out = (float*)d_out;
    float* ws  = (float*)d_ws;   // uses 2560 * 4 B = 10 KB

    pack_weights<<<1, 256, 0, stream>>>(W1, b1, W2, ws);

    const int nrows  = in_sizes[0] / 16;   // (bs*num_p)*4 heads = 262144
    const int groups = nrows / 16;         // 16384 wave-groups
    const int grid   = groups / 4;         // 4 waves per 256-thread block
    subattn_mfma<<<grid, 256, 0, stream>>>(q, k, v, pe, ws, out);
}